// Round 1
// baseline (390.905 us; speedup 1.0000x reference)
//
#include <hip/hip_runtime.h>

#define EMB 768
#define NH 12
#define HD 64
#define BBATCH 8
#define LL 1024
#define BL (BBATCH * LL)  // 8192

typedef __attribute__((ext_vector_type(8))) short bf16x8;
typedef __attribute__((ext_vector_type(4))) float f32x4;

__device__ __forceinline__ unsigned int f2bfu(float f) {
  unsigned int u = __builtin_bit_cast(unsigned int, f);
  return (u + 0x7FFFu + ((u >> 16) & 1u)) >> 16;  // RNE f32->bf16
}

__device__ __forceinline__ f32x4 mfma16(bf16x8 a, bf16x8 b, f32x4 c) {
  return __builtin_amdgcn_mfma_f32_16x16x32_bf16(a, b, c, 0, 0, 0);
}

// ---------------- weight f32 -> bf16 conversion ----------------
__global__ __launch_bounds__(256) void convert_w_kernel(
    const float* __restrict__ wq, const float* __restrict__ wk,
    const float* __restrict__ wv, const float* __restrict__ wd,
    unsigned short* __restrict__ out) {
  const int n = EMB * EMB;
  int e = (blockIdx.x * 256 + threadIdx.x) * 4;
  int which = e / n;
  int off = e - which * n;
  const float* src = (which == 0) ? wq : (which == 1) ? wk : (which == 2) ? wv : wd;
  float4 v4 = *reinterpret_cast<const float4*>(src + off);
  uint2 o;
  o.x = f2bfu(v4.x) | (f2bfu(v4.y) << 16);
  o.y = f2bfu(v4.z) | (f2bfu(v4.w) << 16);
  *reinterpret_cast<uint2*>(out + e) = o;
}

// ---------------- GEMM: out = X @ W^T + bias ----------------
// MODE 0: bf16 out, head-split [b,h,l,d], scaled (Q uses 1/sqrt(768))
// MODE 1: bf16 out, transposed  [b,h,d,l] (V)
// MODE 2: f32 out [8192,768] (dense); input X is bf16
template <int MODE>
__global__ __launch_bounds__(256) void gemm_xwt_kernel(
    const void* __restrict__ Xv, const unsigned short* __restrict__ W,
    const float* __restrict__ bias, void* __restrict__ outp, float out_scale) {
  constexpr bool IN_F32 = (MODE != 2);
  extern __shared__ char smem[];
  unsigned short* Ab = reinterpret_cast<unsigned short*>(smem);  // [128][32] bf16, swizzled
  unsigned short* Bb = Ab + 128 * 32;

  const int t = threadIdx.x;
  const int lane = t & 63, wid = t >> 6;
  const int wr = wid >> 1, wc = wid & 1;
  const int lrow = lane & 15, lgrp = lane >> 4;
  const int bm0 = blockIdx.x * 128, bn0 = blockIdx.y * 128;

  f32x4 acc[4][4];
#pragma unroll
  for (int i = 0; i < 4; ++i)
#pragma unroll
    for (int j = 0; j < 4; ++j) acc[i][j] = (f32x4){0.f, 0.f, 0.f, 0.f};

  float4 aF[2][2];
  uint4 aB[2];
  uint4 bB[2];

  const int ar = t >> 2, as = t & 3;        // f32 A staging: row pair (ar, ar+64), slot as
  const int rb = t >> 1, sb = (t & 1) * 2;  // bf16 staging: row rb, slots sb, sb+1

  auto load_regs = [&](int kt) {
    const int k0 = kt * 32;
    if constexpr (IN_F32) {
      const float* X = reinterpret_cast<const float*>(Xv);
      const float* g0 = X + (size_t)(bm0 + ar) * EMB + k0 + as * 8;
      aF[0][0] = reinterpret_cast<const float4*>(g0)[0];
      aF[0][1] = reinterpret_cast<const float4*>(g0)[1];
      const float* g1 = g0 + (size_t)64 * EMB;
      aF[1][0] = reinterpret_cast<const float4*>(g1)[0];
      aF[1][1] = reinterpret_cast<const float4*>(g1)[1];
    } else {
      const unsigned short* X = reinterpret_cast<const unsigned short*>(Xv);
      const uint4* g = reinterpret_cast<const uint4*>(X + (size_t)(bm0 + rb) * EMB + k0 + sb * 8);
      aB[0] = g[0];
      aB[1] = g[1];
    }
    const uint4* gw = reinterpret_cast<const uint4*>(W + (size_t)(bn0 + rb) * EMB + k0 + sb * 8);
    bB[0] = gw[0];
    bB[1] = gw[1];
  };

  auto write_lds = [&]() {
    if constexpr (IN_F32) {
#pragma unroll
      for (int it = 0; it < 2; ++it) {
        int r = ar + it * 64;
        uint4 pk;
        pk.x = f2bfu(aF[it][0].x) | (f2bfu(aF[it][0].y) << 16);
        pk.y = f2bfu(aF[it][0].z) | (f2bfu(aF[it][0].w) << 16);
        pk.z = f2bfu(aF[it][1].x) | (f2bfu(aF[it][1].y) << 16);
        pk.w = f2bfu(aF[it][1].z) | (f2bfu(aF[it][1].w) << 16);
        *reinterpret_cast<uint4*>(Ab + r * 32 + ((as ^ (r & 3)) * 8)) = pk;
      }
    } else {
      *reinterpret_cast<uint4*>(Ab + rb * 32 + ((sb ^ (rb & 3)) * 8)) = aB[0];
      *reinterpret_cast<uint4*>(Ab + rb * 32 + (((sb + 1) ^ (rb & 3)) * 8)) = aB[1];
    }
    *reinterpret_cast<uint4*>(Bb + rb * 32 + ((sb ^ (rb & 3)) * 8)) = bB[0];
    *reinterpret_cast<uint4*>(Bb + rb * 32 + (((sb + 1) ^ (rb & 3)) * 8)) = bB[1];
  };

  auto compute = [&]() {
    bf16x8 a[4], b[4];
    const int sw = (lgrp ^ (lrow & 3)) * 8;
#pragma unroll
    for (int i = 0; i < 4; ++i) {
      int r = wr * 64 + i * 16 + lrow;
      a[i] = *reinterpret_cast<const bf16x8*>(Ab + r * 32 + sw);
      int c = wc * 64 + i * 16 + lrow;
      b[i] = *reinterpret_cast<const bf16x8*>(Bb + c * 32 + sw);
    }
#pragma unroll
    for (int i = 0; i < 4; ++i)
#pragma unroll
      for (int j = 0; j < 4; ++j) acc[i][j] = mfma16(a[i], b[j], acc[i][j]);
  };

  load_regs(0);
  write_lds();
  __syncthreads();
#pragma unroll 1
  for (int kt = 0; kt < 24; ++kt) {
    if (kt < 23) load_regs(kt + 1);  // issue next-tile loads early (hide HBM latency)
    compute();
    __syncthreads();
    if (kt < 23) {
      write_lds();
      __syncthreads();
    }
  }

  if constexpr (MODE == 0) {
    unsigned short* out = reinterpret_cast<unsigned short*>(outp);
#pragma unroll
    for (int jj = 0; jj < 4; ++jj) {
      int C = bn0 + wc * 64 + jj * 16 + lrow;
      float bv = bias[C];
      int hh = C >> 6, dd = C & 63;
#pragma unroll
      for (int i = 0; i < 4; ++i)
#pragma unroll
        for (int j2 = 0; j2 < 4; ++j2) {
          int R = bm0 + wr * 64 + i * 16 + lgrp * 4 + j2;
          int bidx = R >> 10, l = R & 1023;
          out[(((size_t)(bidx * NH + hh) * 1024 + l) << 6) + dd] =
              (unsigned short)f2bfu((acc[i][jj][j2] + bv) * out_scale);
        }
    }
  }

  if constexpr (MODE == 1) {
    __syncthreads();  // staging reads done; reuse smem as transpose buffer
    unsigned short* T = reinterpret_cast<unsigned short*>(smem);  // [128][136]
#pragma unroll
    for (int jj = 0; jj < 4; ++jj) {
      int cl = wc * 64 + jj * 16 + lrow;
      float bv = bias[bn0 + cl];
#pragma unroll
      for (int i = 0; i < 4; ++i)
#pragma unroll
        for (int j2 = 0; j2 < 4; ++j2) {
          int rl = wr * 64 + i * 16 + lgrp * 4 + j2;
          T[cl * 136 + rl] = (unsigned short)f2bfu(acc[i][jj][j2] + bv);
        }
    }
    __syncthreads();
    unsigned short* out = reinterpret_cast<unsigned short*>(outp);
    int cl = t >> 1, rh = (t & 1) * 64;
    int C = bn0 + cl, hh = C >> 6, dd = C & 63;
    int Rg = bm0 + rh, bidx = Rg >> 10, l0 = Rg & 1023;
    size_t obase = ((size_t)(bidx * NH + hh) * 64 + dd) * 1024 + l0;
#pragma unroll
    for (int q8 = 0; q8 < 8; ++q8) {
      uint4 val = *reinterpret_cast<const uint4*>(T + cl * 136 + rh + q8 * 8);
      *reinterpret_cast<uint4*>(out + obase + q8 * 8) = val;
    }
  }

  if constexpr (MODE == 2) {
    float* out = reinterpret_cast<float*>(outp);
#pragma unroll
    for (int jj = 0; jj < 4; ++jj) {
      int C = bn0 + wc * 64 + jj * 16 + lrow;
      float bv = bias[C];
#pragma unroll
      for (int i = 0; i < 4; ++i)
#pragma unroll
        for (int j2 = 0; j2 < 4; ++j2) {
          int R = bm0 + wr * 64 + i * 16 + lgrp * 4 + j2;
          out[(size_t)R * EMB + C] = acc[i][jj][j2] + bv;
        }
    }
  }
}

// ---------------- attention: S=QK^T (scale folded into Q), softmax, attn_w, PV ----------------
// grid (64 q-tiles, 96 pairs); block 256 = 4 waves; each block: 16 q-rows, full k=1024.
__global__ __launch_bounds__(256) void attn_kernel(
    const unsigned short* __restrict__ qh, const unsigned short* __restrict__ kh,
    const unsigned short* __restrict__ vhT, float* __restrict__ attn_w,
    unsigned short* __restrict__ concat) {
  __shared__ unsigned short Pl[16 * 1024];  // P tile, bf16, XOR-swizzled rows (2KB stride)
  __shared__ float red[2][4][16];

  const int t = threadIdx.x;
  const int lane = t & 63, w = t >> 6;
  const int lrow = lane & 15, lgrp = lane >> 4;
  const int qt = blockIdx.x, pair = blockIdx.y;
  const int b = pair / NH, h = pair - b * NH;
  const int q0 = qt * 16;
  const unsigned short* qbase = qh + (size_t)pair * (LL * HD);
  const unsigned short* kbase = kh + (size_t)pair * (LL * HD);
  const unsigned short* vbase = vhT + (size_t)pair * (HD * LL);

  bf16x8 aq[2];
#pragma unroll
  for (int c = 0; c < 2; ++c)
    aq[c] = *reinterpret_cast<const bf16x8*>(qbase + (size_t)(q0 + lrow) * HD + c * 32 + lgrp * 8);

  f32x4 acc[16];
#pragma unroll
  for (int f = 0; f < 16; ++f) acc[f] = (f32x4){0.f, 0.f, 0.f, 0.f};

  const int k0 = w * 256;  // wave's 256 k-columns
#pragma unroll
  for (int f = 0; f < 16; ++f) {
    const unsigned short* kr = kbase + (size_t)(k0 + f * 16 + lrow) * HD + lgrp * 8;
    bf16x8 b0 = *reinterpret_cast<const bf16x8*>(kr);
    bf16x8 b1 = *reinterpret_cast<const bf16x8*>(kr + 32);
    acc[f] = mfma16(aq[0], b0, acc[f]);
    acc[f] = mfma16(aq[1], b1, acc[f]);
  }

  // ---- softmax (rows = 16 q-rows; cols split across 4 waves) ----
  float m0[4], s0[4];
#pragma unroll
  for (int j = 0; j < 4; ++j) m0[j] = acc[0][j];
#pragma unroll
  for (int f = 1; f < 16; ++f)
#pragma unroll
    for (int j = 0; j < 4; ++j) m0[j] = fmaxf(m0[j], acc[f][j]);
#pragma unroll
  for (int mask = 1; mask < 16; mask <<= 1)
#pragma unroll
    for (int j = 0; j < 4; ++j) m0[j] = fmaxf(m0[j], __shfl_xor(m0[j], mask));
  if ((lane & 15) == 0) {
#pragma unroll
    for (int j = 0; j < 4; ++j) red[0][w][lgrp * 4 + j] = m0[j];
  }
  __syncthreads();
  float M[4];
#pragma unroll
  for (int j = 0; j < 4; ++j) {
    int r = lgrp * 4 + j;
    M[j] = fmaxf(fmaxf(red[0][0][r], red[0][1][r]), fmaxf(red[0][2][r], red[0][3][r]));
    s0[j] = 0.f;
  }
#pragma unroll
  for (int f = 0; f < 16; ++f)
#pragma unroll
    for (int j = 0; j < 4; ++j) {
      float p = __expf(acc[f][j] - M[j]);
      acc[f][j] = p;
      s0[j] += p;
    }
#pragma unroll
  for (int mask = 1; mask < 16; mask <<= 1)
#pragma unroll
    for (int j = 0; j < 4; ++j) s0[j] += __shfl_xor(s0[j], mask);
  if ((lane & 15) == 0) {
#pragma unroll
    for (int j = 0; j < 4; ++j) red[1][w][lgrp * 4 + j] = s0[j];
  }
  __syncthreads();
  float inv[4];
#pragma unroll
  for (int j = 0; j < 4; ++j) {
    int r = lgrp * 4 + j;
    inv[j] = 1.0f / (red[1][0][r] + red[1][1][r] + red[1][2][r] + red[1][3][r]);
  }

  // ---- write attn_w (f32, streaming) + P (bf16) into swizzled LDS ----
  float* awp = attn_w + (size_t)pair * (LL * LL);
#pragma unroll
  for (int f = 0; f < 16; ++f) {
    int col = k0 + f * 16 + lrow;
#pragma unroll
    for (int j = 0; j < 4; ++j) {
      int prow = lgrp * 4 + j;
      float v = acc[f][j] * inv[j];
      __builtin_nontemporal_store(v, awp + (size_t)(q0 + prow) * LL + col);
      int byte = (prow * 2048 + col * 2) ^ ((prow & 7) << 4);
      *reinterpret_cast<unsigned short*>(reinterpret_cast<char*>(Pl) + byte) =
          (unsigned short)f2bfu(v);
    }
  }
  __syncthreads();

  // ---- PV: O[16 x 16d-slice per wave] = P[16 x 1024] * vh[1024 x 64] ----
  f32x4 o = (f32x4){0.f, 0.f, 0.f, 0.f};
  const unsigned short* vrow = vbase + (size_t)(w * 16 + lrow) * LL;
#pragma unroll
  for (int kk = 0; kk < 32; ++kk) {
    int byte = (lrow * 2048 + (kk * 32 + lgrp * 8) * 2) ^ ((lrow & 7) << 4);
    bf16x8 pa = *reinterpret_cast<const bf16x8*>(reinterpret_cast<char*>(Pl) + byte);
    bf16x8 vb = *reinterpret_cast<const bf16x8*>(vrow + kk * 32 + lgrp * 8);
    o = mfma16(pa, vb, o);
  }
#pragma unroll
  for (int j = 0; j < 4; ++j) {
    int row = q0 + lgrp * 4 + j;
    int cc = h * 64 + w * 16 + lrow;
    concat[((size_t)b * LL + row) * EMB + cc] = (unsigned short)f2bfu(o[j]);
  }
}

extern "C" void kernel_launch(void* const* d_in, const int* in_sizes, int n_in,
                              void* d_out, int out_size, void* d_ws, size_t ws_size,
                              hipStream_t stream) {
  const float* v = (const float*)d_in[0];
  const float* k = (const float*)d_in[1];
  const float* q = (const float*)d_in[2];
  const float* wq_w = (const float*)d_in[3];
  const float* wq_b = (const float*)d_in[4];
  const float* wk_w = (const float*)d_in[5];
  const float* wk_b = (const float*)d_in[6];
  const float* wv_w = (const float*)d_in[7];
  const float* wv_b = (const float*)d_in[8];
  const float* dw = (const float*)d_in[9];
  const float* db = (const float*)d_in[10];

  float* out_attn = (float*)d_out;                // [8,1024,768]
  float* out_w = out_attn + (size_t)BL * EMB;     // [8,12,1024,1024]

  // workspace layout (ushort): 4 weight mats + qh + kh + vhT + concat = 55,050,240 B
  if (ws_size < 55050240u) return;
  unsigned short* ws = (unsigned short*)d_ws;
  unsigned short* wqb16 = ws;
  unsigned short* wkb16 = wqb16 + EMB * EMB;
  unsigned short* wvb16 = wkb16 + EMB * EMB;
  unsigned short* wdb16 = wvb16 + EMB * EMB;
  unsigned short* qhb = wdb16 + EMB * EMB;
  unsigned short* khb = qhb + (size_t)BL * EMB;
  unsigned short* vtb = khb + (size_t)BL * EMB;
  unsigned short* cat = vtb + (size_t)BL * EMB;

  convert_w_kernel<<<dim3(2304), dim3(256), 0, stream>>>(wq_w, wk_w, wv_w, dw, ws);

  const float scale = 0.036084391824351615f;  // 1/sqrt(768) folded into Q projection
  dim3 gg(64, 6);
  gemm_xwt_kernel<0><<<gg, 256, 16384, stream>>>(q, wqb16, wq_b, qhb, scale);
  gemm_xwt_kernel<0><<<gg, 256, 16384, stream>>>(k, wkb16, wk_b, khb, 1.0f);
  gemm_xwt_kernel<1><<<gg, 256, 128 * 136 * 2, stream>>>(v, wvb16, wv_b, vtb, 1.0f);

  attn_kernel<<<dim3(64, 96), 256, 0, stream>>>(qhb, khb, vtb, out_w, cat);

  gemm_xwt_kernel<2><<<gg, 256, 16384, stream>>>(cat, wdb16, db, out_attn, 1.0f);
}